// Round 1
// baseline (127.047 us; speedup 1.0000x reference)
//
#include <hip/hip_runtime.h>

// SSIM (window=3, stride=3, pad=1) fused single-pass + mean reduction.
// Windows tile the input (stride==window), so each input pixel is read once.

#define HW     512
#define OHW    171            // (512 + 2*1 - 3)/3 + 1
#define NPLANE 48             // 16 batch * 3 channels
#define NOUT   (NPLANE * OHW * OHW)   // 1,403,568
#define NBLK   2048
#define TPB    256

__global__ __launch_bounds__(TPB) void ssim_main(
    const float* __restrict__ img1, const float* __restrict__ img2,
    const float* __restrict__ win, float* __restrict__ partial) {
  // Window is identical per channel; first 9 floats suffice. Uniform address,
  // L1-cached broadcast.
  float w[9];
#pragma unroll
  for (int i = 0; i < 9; ++i) w[i] = win[i];

  const float C1 = 0.01f * 0.01f;
  const float C2 = 0.03f * 0.03f;

  float acc = 0.0f;
  for (int idx = blockIdx.x * TPB + threadIdx.x; idx < NOUT; idx += NBLK * TPB) {
    int ox = idx % OHW;
    int t  = idx / OHW;
    int oy = t % OHW;
    int p  = t / OHW;                 // plane 0..47
    const float* a = img1 + (size_t)p * HW * HW;
    const float* b = img2 + (size_t)p * HW * HW;
    int ix0 = 3 * ox - 1;             // window start (pad=1)
    int iy0 = 3 * oy - 1;

    float s1 = 0.f, s2 = 0.f, s11 = 0.f, s22 = 0.f, s12 = 0.f;
#pragma unroll
    for (int ky = 0; ky < 3; ++ky) {
      int iy = iy0 + ky;
      if (iy < 0) continue;           // only oy==0 pads; iy<=511 always
      const float* ar = a + (size_t)iy * HW;
      const float* br = b + (size_t)iy * HW;
#pragma unroll
      for (int kx = 0; kx < 3; ++kx) {
        int ix = ix0 + kx;
        if (ix < 0) continue;         // only ox==0 pads; ix<=511 always
        float wv = w[ky * 3 + kx];
        float x = ar[ix];
        float y = br[ix];
        s1  += wv * x;
        s2  += wv * y;
        s11 += wv * x * x;
        s22 += wv * y * y;
        s12 += wv * x * y;
      }
    }
    float mu11 = s1 * s1, mu22 = s2 * s2, mu12 = s1 * s2;
    float sg1 = s11 - mu11, sg2 = s22 - mu22, sg12 = s12 - mu12;
    float num = (2.0f * mu12 + C1) * (2.0f * sg12 + C2);
    float den = (mu11 + mu22 + C1) * (sg1 + sg2 + C2);
    acc += num / den;
  }

  // wave (64) shuffle reduce
#pragma unroll
  for (int off = 32; off > 0; off >>= 1) acc += __shfl_down(acc, off, 64);
  __shared__ float wsum[TPB / 64];
  int lane = threadIdx.x & 63, wid = threadIdx.x >> 6;
  if (lane == 0) wsum[wid] = acc;
  __syncthreads();
  if (threadIdx.x == 0) {
    float s = 0.f;
#pragma unroll
    for (int i = 0; i < TPB / 64; ++i) s += wsum[i];
    partial[blockIdx.x] = s;          // every block writes its slot: no init needed
  }
}

__global__ __launch_bounds__(256) void ssim_final(
    const float* __restrict__ partial, float* __restrict__ out) {
  float acc = 0.f;
  for (int i = threadIdx.x; i < NBLK; i += 256) acc += partial[i];
#pragma unroll
  for (int off = 32; off > 0; off >>= 1) acc += __shfl_down(acc, off, 64);
  __shared__ float wsum[4];
  int lane = threadIdx.x & 63, wid = threadIdx.x >> 6;
  if (lane == 0) wsum[wid] = acc;
  __syncthreads();
  if (threadIdx.x == 0) {
    float s = 0.f;
#pragma unroll
    for (int i = 0; i < 4; ++i) s += wsum[i];
    out[0] = s / (float)NOUT;
  }
}

extern "C" void kernel_launch(void* const* d_in, const int* in_sizes, int n_in,
                              void* d_out, int out_size, void* d_ws, size_t ws_size,
                              hipStream_t stream) {
  const float* img1 = (const float*)d_in[0];
  const float* img2 = (const float*)d_in[1];
  const float* win  = (const float*)d_in[2];
  float* partial = (float*)d_ws;       // NBLK floats
  float* out = (float*)d_out;

  ssim_main<<<NBLK, TPB, 0, stream>>>(img1, img2, win, partial);
  ssim_final<<<1, 256, 0, stream>>>(partial, out);
}